// Round 1
// baseline (2868.798 us; speedup 1.0000x reference)
//
#include <hip/hip_runtime.h>

#define H 128
#define RREL 8

__global__ void zero_kernel(float* p, long n) {
    long i = (long)blockIdx.x * blockDim.x + threadIdx.x;
    long stride = (long)gridDim.x * blockDim.x;
    for (; i < n; i += stride) p[i] = 0.f;
}

__global__ void count_kernel(const int* __restrict__ ei, const int* __restrict__ et,
                             float* __restrict__ cnt, int E) {
    int e = blockIdx.x * 256 + threadIdx.x;
    if (e >= E) return;
    int d = ei[E + e];
    int r = et[e];
    atomicAdd(&cnt[d * RREL + r], 1.0f);
}

__global__ void inv_kernel(float* cnt, int n) {
    int i = blockIdx.x * 256 + threadIdx.x;
    if (i >= n) return;
    float c = cnt[i];
    cnt[i] = 1.0f / fmaxf(c, 1.0f);
}

// xw[c][n][f] = sum_d X[n][d] * W[c][d][f]   (W base pre-offset to relation chunk)
__global__ __launch_bounds__(256) void gemm_xw_kernel(const float* __restrict__ X,
                                                      const float* __restrict__ W,
                                                      float* __restrict__ xw, int N) {
    const int c = blockIdx.y;
    const int m0 = blockIdx.x * 64;
    const float* Wr = W + (size_t)c * H * H;
    __shared__ float Xs[64][33];
    __shared__ float Ws[32][H];
    const int t = threadIdx.x;
    const int rb = (t >> 5) * 8;
    const int cb = (t & 31) * 4;
    float acc[8][4] = {};
    for (int kk = 0; kk < H; kk += 32) {
        for (int l = t; l < 64 * 32; l += 256) {
            int i = l >> 5, j = l & 31;
            int n = m0 + i;
            Xs[i][j] = (n < N) ? X[(size_t)n * H + kk + j] : 0.f;
        }
        for (int l = t; l < 32 * H; l += 256) {
            int d = l >> 7, f = l & 127;
            Ws[d][f] = Wr[(size_t)(kk + d) * H + f];
        }
        __syncthreads();
#pragma unroll
        for (int k = 0; k < 32; ++k) {
            float4 w = *(const float4*)&Ws[k][cb];
#pragma unroll
            for (int i = 0; i < 8; ++i) {
                float xv = Xs[rb + i][k];
                acc[i][0] = fmaf(xv, w.x, acc[i][0]);
                acc[i][1] = fmaf(xv, w.y, acc[i][1]);
                acc[i][2] = fmaf(xv, w.z, acc[i][2]);
                acc[i][3] = fmaf(xv, w.w, acc[i][3]);
            }
        }
        __syncthreads();
    }
    for (int i = 0; i < 8; ++i) {
        int n = m0 + rb + i;
        if (n < N) {
            *(float4*)&xw[((size_t)c * N + n) * H + cb] =
                make_float4(acc[i][0], acc[i][1], acc[i][2], acc[i][3]);
        }
    }
}

// out[n][f] = act(acc_in[n][f] + X[n][:] @ Wroot[:][f] + bias[f]); in-place safe
__global__ __launch_bounds__(256) void gemm_root_kernel(const float* __restrict__ X,
                                                        const float* __restrict__ Wroot,
                                                        const float* __restrict__ bias,
                                                        const float* __restrict__ acc_in,
                                                        float* __restrict__ out,
                                                        int N, int do_relu) {
    const int m0 = blockIdx.x * 64;
    __shared__ float Xs[64][33];
    __shared__ float Ws[32][H];
    const int t = threadIdx.x;
    const int rb = (t >> 5) * 8;
    const int cb = (t & 31) * 4;
    float acc[8][4] = {};
    for (int kk = 0; kk < H; kk += 32) {
        for (int l = t; l < 64 * 32; l += 256) {
            int i = l >> 5, j = l & 31;
            int n = m0 + i;
            Xs[i][j] = (n < N) ? X[(size_t)n * H + kk + j] : 0.f;
        }
        for (int l = t; l < 32 * H; l += 256) {
            int d = l >> 7, f = l & 127;
            Ws[d][f] = Wroot[(size_t)(kk + d) * H + f];
        }
        __syncthreads();
#pragma unroll
        for (int k = 0; k < 32; ++k) {
            float4 w = *(const float4*)&Ws[k][cb];
#pragma unroll
            for (int i = 0; i < 8; ++i) {
                float xv = Xs[rb + i][k];
                acc[i][0] = fmaf(xv, w.x, acc[i][0]);
                acc[i][1] = fmaf(xv, w.y, acc[i][1]);
                acc[i][2] = fmaf(xv, w.z, acc[i][2]);
                acc[i][3] = fmaf(xv, w.w, acc[i][3]);
            }
        }
        __syncthreads();
    }
    for (int i = 0; i < 8; ++i) {
        int n = m0 + rb + i;
        if (n < N) {
            float4 a = *(const float4*)&acc_in[(size_t)n * H + cb];
            float4 v;
            v.x = acc[i][0] + a.x + bias[cb + 0];
            v.y = acc[i][1] + a.y + bias[cb + 1];
            v.z = acc[i][2] + a.z + bias[cb + 2];
            v.w = acc[i][3] + a.w + bias[cb + 3];
            if (do_relu) {
                v.x = fmaxf(v.x, 0.f); v.y = fmaxf(v.y, 0.f);
                v.z = fmaxf(v.z, 0.f); v.w = fmaxf(v.w, 0.f);
            }
            *(float4*)&out[(size_t)n * H + cb] = v;
        }
    }
}

// 32 threads per edge, each handling 4 floats
__global__ void scatter_kernel(const float* __restrict__ xw, const float* __restrict__ inv,
                               const int* __restrict__ ei, const int* __restrict__ et,
                               float* __restrict__ acc, int E, int N, int r0, int C) {
    long g = (long)blockIdx.x * 256 + threadIdx.x;
    long e = g >> 5;
    if (e >= E) return;
    int j = (int)(g & 31);
    int r = et[e] - r0;
    if ((unsigned)r >= (unsigned)C) return;
    int s = ei[e];
    int d = ei[E + e];
    float iv = inv[(size_t)d * RREL + r + r0];
    const float4 v = *(const float4*)&xw[((size_t)r * N + s) * H + j * 4];
    float* a = &acc[(size_t)d * H + j * 4];
    atomicAdd(a + 0, v.x * iv);
    atomicAdd(a + 1, v.y * iv);
    atomicAdd(a + 2, v.z * iv);
    atomicAdd(a + 3, v.w * iv);
}

extern "C" void kernel_launch(void* const* d_in, const int* in_sizes, int n_in,
                              void* d_out, int out_size, void* d_ws, size_t ws_size,
                              hipStream_t stream) {
    const int* edge_index = (const int*)d_in[0];
    const int* edge_type  = (const int*)d_in[1];
    const float* node_emb = (const float*)d_in[2];
    const float* W1    = (const float*)d_in[3];
    const float* root1 = (const float*)d_in[4];
    const float* b1    = (const float*)d_in[5];
    const float* W2    = (const float*)d_in[6];
    const float* root2 = (const float*)d_in[7];
    const float* b2    = (const float*)d_in[8];
    float* out = (float*)d_out;

    const int E = in_sizes[1];
    const int N = in_sizes[2] / H;

    // workspace layout: cnt[N*R] | bufA[N*H] | xw[C*N*H]
    float* cnt  = (float*)d_ws;
    float* bufA = cnt + (size_t)N * RREL;
    float* xw   = bufA + (size_t)N * H;
    size_t base_bytes = ((size_t)N * RREL + (size_t)N * H) * sizeof(float);
    int C = 1;
    for (int c = RREL; c >= 1; c >>= 1) {
        if (base_bytes + (size_t)c * N * H * sizeof(float) <= ws_size) { C = c; break; }
    }

    zero_kernel<<<2048, 256, 0, stream>>>(cnt, (long)N * RREL + (long)N * H);
    zero_kernel<<<2048, 256, 0, stream>>>(out, (long)N * H);
    count_kernel<<<(E + 255) / 256, 256, 0, stream>>>(edge_index, edge_type, cnt, E);
    inv_kernel<<<(N * RREL + 255) / 256, 256, 0, stream>>>(cnt, N * RREL);

    const int gm = (N + 63) / 64;
    const int scatter_blocks = (int)(((long)E * 32 + 255) / 256);

    // layer 1: aggregate into bufA, then h = relu(bufA + x@root1 + b1) in-place
    for (int r0 = 0; r0 < RREL; r0 += C) {
        gemm_xw_kernel<<<dim3(gm, C), 256, 0, stream>>>(node_emb, W1 + (size_t)r0 * H * H, xw, N);
        scatter_kernel<<<scatter_blocks, 256, 0, stream>>>(xw, cnt, edge_index, edge_type,
                                                           bufA, E, N, r0, C);
    }
    gemm_root_kernel<<<dim3(gm, 1), 256, 0, stream>>>(node_emb, root1, b1, bufA, bufA, N, 1);

    // layer 2: aggregate into out, then out += h@root2 + b2 in-place
    for (int r0 = 0; r0 < RREL; r0 += C) {
        gemm_xw_kernel<<<dim3(gm, C), 256, 0, stream>>>(bufA, W2 + (size_t)r0 * H * H, xw, N);
        scatter_kernel<<<scatter_blocks, 256, 0, stream>>>(xw, cnt, edge_index, edge_type,
                                                           out, E, N, r0, C);
    }
    gemm_root_kernel<<<dim3(gm, 1), 256, 0, stream>>>(bufA, root2, b2, out, out, N, 0);
}

// Round 2
// 501.602 us; speedup vs baseline: 5.7193x; 5.7193x over previous
//
#include <hip/hip_runtime.h>

#define H 128
#define RREL 8
#define KTOT 1152  // RREL*H + H

typedef short bf16x8 __attribute__((ext_vector_type(8)));
typedef float f32x4 __attribute__((ext_vector_type(4)));
typedef unsigned short u16x8 __attribute__((ext_vector_type(8)));

static __device__ __forceinline__ unsigned short f2bf(float f) {
    unsigned int u = __float_as_uint(f);
    unsigned int r = (u + 0x7fffu + ((u >> 16) & 1u)) >> 16;
    return (unsigned short)r;
}

__global__ void zero_kernel(float* p, long n) {
    long i = (long)blockIdx.x * blockDim.x + threadIdx.x;
    long stride = (long)gridDim.x * blockDim.x;
    for (; i < n; i += stride) p[i] = 0.f;
}

__global__ void count_kernel(const int* __restrict__ ei, const int* __restrict__ et,
                             float* __restrict__ cnt, int E) {
    int e = blockIdx.x * 256 + threadIdx.x;
    if (e >= E) return;
    int d = ei[E + e];
    int r = et[e];
    atomicAdd(&cnt[(size_t)d * RREL + r], 1.0f);
}

// deg[d] = total in-degree; cnt -> inv in place
__global__ void deginv_kernel(float* __restrict__ cnt, int* __restrict__ deg, int N) {
    int d = blockIdx.x * 256 + threadIdx.x;
    if (d >= N) return;
    float s = 0.f;
#pragma unroll
    for (int r = 0; r < RREL; ++r) s += cnt[(size_t)d * RREL + r];
    deg[d] = (int)(s + 0.5f);
#pragma unroll
    for (int r = 0; r < RREL; ++r) {
        float c = cnt[(size_t)d * RREL + r];
        cnt[(size_t)d * RREL + r] = 1.0f / fmaxf(c, 1.0f);
    }
}

// per-block exclusive scan of deg (256/block) -> rowptr local, bsum[b] = block total
__global__ void scan_block_kernel(const int* __restrict__ deg, int* __restrict__ rowptr,
                                  int* __restrict__ bsum, int N) {
    __shared__ int s[256];
    int t = threadIdx.x;
    int d = blockIdx.x * 256 + t;
    int v = (d < N) ? deg[d] : 0;
    s[t] = v;
    __syncthreads();
#pragma unroll
    for (int off = 1; off < 256; off <<= 1) {
        int u = 0;
        if (t >= off) u = s[t - off];
        __syncthreads();
        s[t] += u;
        __syncthreads();
    }
    if (d < N) rowptr[d] = s[t] - v;
    if (t == 255) bsum[blockIdx.x] = s[255];
}

// single-block exclusive scan of block sums; writes rowptr[N] = grand total
__global__ void scan_top_kernel(const int* __restrict__ bsum, int* __restrict__ boff,
                                int* __restrict__ rowptr, int nb, int N) {
    __shared__ int s[256];
    int t = threadIdx.x;
    int v = (t < nb) ? bsum[t] : 0;
    s[t] = v;
    __syncthreads();
#pragma unroll
    for (int off = 1; off < 256; off <<= 1) {
        int u = 0;
        if (t >= off) u = s[t - off];
        __syncthreads();
        s[t] += u;
        __syncthreads();
    }
    boff[t] = s[t] - v;
    if (t == nb - 1) rowptr[N] = s[t];
}

__global__ void add_off_kernel(int* __restrict__ rowptr, const int* __restrict__ boff, int N) {
    int d = blockIdx.x * 256 + threadIdx.x;
    if (d < N) rowptr[d] += boff[d >> 8];
}

__global__ void fill_kernel(const int* __restrict__ ei, int* __restrict__ cursor,
                            const int* __restrict__ rowptr, int* __restrict__ csr, int E) {
    int e = blockIdx.x * 256 + threadIdx.x;
    if (e >= E) return;
    int d = ei[E + e];
    int pos = rowptr[d] + atomicAdd(&cursor[d], 1);
    csr[pos] = e;
}

// Build B^T (bf16): WT[f][k], k = r*128+d for k<1024 (W[r][d][f]), else root[k-1024][f]
__global__ void wcat_kernel(const float* __restrict__ W1, const float* __restrict__ r1,
                            const float* __restrict__ W2, const float* __restrict__ r2,
                            unsigned short* __restrict__ WT1, unsigned short* __restrict__ WT2) {
    int id = blockIdx.x * 256 + threadIdx.x;
    if (id >= 2 * H * KTOT) return;
    int b = id / (H * KTOT);
    int rem = id - b * (H * KTOT);
    int f = rem / KTOT;
    int k = rem - f * KTOT;
    const float* W = b ? W2 : W1;
    const float* rt = b ? r2 : r1;
    float v = (k < RREL * H) ? W[(size_t)(k >> 7) * H * H + (size_t)(k & 127) * H + f]
                             : rt[(size_t)(k - RREL * H) * H + f];
    (b ? WT2 : WT1)[(size_t)f * KTOT + k] = f2bf(v);
}

// one wave per dst: A[d-n0][r*128+f] = inv[d][r] * sum_{in-edges rel r} src[s][f] (bf16)
//                   A[d-n0][1024+f] = src[d][f] (bf16)
__global__ __launch_bounds__(256) void gather_kernel(const float* __restrict__ src,
                                                     const float* __restrict__ inv,
                                                     const int* __restrict__ rowptr,
                                                     const int* __restrict__ csr,
                                                     const int* __restrict__ ei,
                                                     const int* __restrict__ et,
                                                     unsigned short* __restrict__ A,
                                                     int n0, int n1, int E) {
    const int t = threadIdx.x;
    int d = n0 + blockIdx.x * 4 + (t >> 6);
    if (d >= n1) return;
    const int l = t & 63;
    int beg = rowptr[d], end = rowptr[d + 1];
    float a0x = 0.f, a0y = 0.f, a1x = 0.f, a1y = 0.f, a2x = 0.f, a2y = 0.f, a3x = 0.f, a3y = 0.f;
    float a4x = 0.f, a4y = 0.f, a5x = 0.f, a5y = 0.f, a6x = 0.f, a6y = 0.f, a7x = 0.f, a7y = 0.f;
    for (int i = beg; i < end; ++i) {
        int e = csr[i];
        int r = et[e];
        int s = ei[e];
        float2 v = *(const float2*)&src[(size_t)s * H + l * 2];
        switch (r) {
            case 0: a0x += v.x; a0y += v.y; break;
            case 1: a1x += v.x; a1y += v.y; break;
            case 2: a2x += v.x; a2y += v.y; break;
            case 3: a3x += v.x; a3y += v.y; break;
            case 4: a4x += v.x; a4y += v.y; break;
            case 5: a5x += v.x; a5y += v.y; break;
            case 6: a6x += v.x; a6y += v.y; break;
            default: a7x += v.x; a7y += v.y; break;
        }
    }
    size_t base = (size_t)(d - n0) * KTOT;
    const float* ivp = &inv[(size_t)d * RREL];
    float ax[8] = {a0x, a1x, a2x, a3x, a4x, a5x, a6x, a7x};
    float ay[8] = {a0y, a1y, a2y, a3y, a4y, a5y, a6y, a7y};
#pragma unroll
    for (int r = 0; r < RREL; ++r) {
        float iv = ivp[r];
        ushort2 u;
        u.x = f2bf(ax[r] * iv);
        u.y = f2bf(ay[r] * iv);
        *(ushort2*)&A[base + r * H + l * 2] = u;
    }
    float2 xv = *(const float2*)&src[(size_t)d * H + l * 2];
    ushort2 u;
    u.x = f2bf(xv.x);
    u.y = f2bf(xv.y);
    *(ushort2*)&A[base + RREL * H + l * 2] = u;
}

// out[n][f] = act(sum_k A[n-n0][k]*B[k][f] + bias[f]);  B^T given as WT[f][k]
__global__ __launch_bounds__(256) void gemm_kernel(const unsigned short* __restrict__ A,
                                                   const unsigned short* __restrict__ WT,
                                                   const float* __restrict__ bias,
                                                   float* __restrict__ out,
                                                   int n0, int n1, int relu) {
    __shared__ unsigned short As[128][72];
    __shared__ unsigned short Bs[128][72];
    const int t = threadIdx.x;
    const int w = t >> 6, l = t & 63;
    const int m_base = blockIdx.x * 128;
    const f32x4 fz = {0.f, 0.f, 0.f, 0.f};
    f32x4 acc[2][8];
#pragma unroll
    for (int mi = 0; mi < 2; ++mi)
#pragma unroll
        for (int n = 0; n < 8; ++n) acc[mi][n] = fz;

    const int rr = t >> 3;
    const int kc = (t & 7) * 8;
    const u16x8 uz = {0, 0, 0, 0, 0, 0, 0, 0};

    for (int kk = 0; kk < KTOT; kk += 64) {
#pragma unroll
        for (int p = 0; p < 4; ++p) {
            int row = p * 32 + rr;
            int gn = n0 + m_base + row;
            u16x8 va = uz;
            if (gn < n1) va = *(const u16x8*)&A[(size_t)(gn - n0) * KTOT + kk + kc];
            *(u16x8*)&As[row][kc] = va;
            u16x8 vb = *(const u16x8*)&WT[(size_t)row * KTOT + kk + kc];
            *(u16x8*)&Bs[row][kc] = vb;
        }
        __syncthreads();
#pragma unroll
        for (int ks = 0; ks < 2; ++ks) {
            int kl = ks * 32 + (l >> 4) * 8;
            bf16x8 a0 = *(const bf16x8*)&As[w * 32 + (l & 15)][kl];
            bf16x8 a1 = *(const bf16x8*)&As[w * 32 + 16 + (l & 15)][kl];
#pragma unroll
            for (int n = 0; n < 8; ++n) {
                bf16x8 b = *(const bf16x8*)&Bs[n * 16 + (l & 15)][kl];
                acc[0][n] = __builtin_amdgcn_mfma_f32_16x16x32_bf16(a0, b, acc[0][n], 0, 0, 0);
                acc[1][n] = __builtin_amdgcn_mfma_f32_16x16x32_bf16(a1, b, acc[1][n], 0, 0, 0);
            }
        }
        __syncthreads();
    }
    const int colb = l & 15, quad = l >> 4;
#pragma unroll
    for (int mi = 0; mi < 2; ++mi) {
#pragma unroll
        for (int n = 0; n < 8; ++n) {
            int col = n * 16 + colb;
            float bv = bias[col];
#pragma unroll
            for (int i = 0; i < 4; ++i) {
                int gn = n0 + m_base + w * 32 + mi * 16 + quad * 4 + i;
                if (gn < n1) {
                    float v = acc[mi][n][i] + bv;
                    if (relu) v = fmaxf(v, 0.f);
                    out[(size_t)gn * H + col] = v;
                }
            }
        }
    }
}

extern "C" void kernel_launch(void* const* d_in, const int* in_sizes, int n_in,
                              void* d_out, int out_size, void* d_ws, size_t ws_size,
                              hipStream_t stream) {
    const int* edge_index = (const int*)d_in[0];
    const int* edge_type  = (const int*)d_in[1];
    const float* node_emb = (const float*)d_in[2];
    const float* W1    = (const float*)d_in[3];
    const float* root1 = (const float*)d_in[4];
    const float* b1    = (const float*)d_in[5];
    const float* W2    = (const float*)d_in[6];
    const float* root2 = (const float*)d_in[7];
    const float* b2    = (const float*)d_in[8];
    float* out = (float*)d_out;

    const int E = in_sizes[1];
    const int N = in_sizes[2] / H;

    // workspace layout (64B-aligned regions)
    char* base = (char*)d_ws;
    size_t off = 0;
    auto take = [&](size_t bytes) { size_t o = off; off = (off + bytes + 63) & ~(size_t)63; return o; };
    float* cnt     = (float*)(base + take((size_t)N * RREL * 4));   // becomes inv in place
    int*   deg     = (int*)  (base + take((size_t)N * 4));
    int*   rowptr  = (int*)  (base + take((size_t)(N + 1) * 4));
    int*   cursor  = (int*)  (base + take((size_t)N * 4));
    int*   bsum    = (int*)  (base + take(256 * 4));
    int*   boff    = (int*)  (base + take(256 * 4));
    int*   csr     = (int*)  (base + take((size_t)E * 4));
    unsigned short* WT1 = (unsigned short*)(base + take((size_t)H * KTOT * 2));
    unsigned short* WT2 = (unsigned short*)(base + take((size_t)H * KTOT * 2));
    float* h       = (float*)(base + take((size_t)N * H * 4));
    size_t a_off = off;
    unsigned short* A = (unsigned short*)(base + a_off);

    // pick node-chunk so A fits in remaining workspace
    size_t avail = (ws_size > a_off) ? (ws_size - a_off) : 0;
    int chunk = N;
    while ((size_t)((chunk + 127) & ~127) * KTOT * 2 > avail && chunk > 1024) chunk = (chunk + 1) / 2;
    chunk = (chunk + 127) & ~127;

    const int nbScan = (N + 255) / 256;

    zero_kernel<<<512, 256, 0, stream>>>(cnt, (long)N * RREL);
    zero_kernel<<<512, 256, 0, stream>>>((float*)cursor, N);
    count_kernel<<<(E + 255) / 256, 256, 0, stream>>>(edge_index, edge_type, cnt, E);
    deginv_kernel<<<nbScan, 256, 0, stream>>>(cnt, deg, N);
    scan_block_kernel<<<nbScan, 256, 0, stream>>>(deg, rowptr, bsum, N);
    scan_top_kernel<<<1, 256, 0, stream>>>(bsum, boff, rowptr, nbScan, N);
    add_off_kernel<<<nbScan, 256, 0, stream>>>(rowptr, boff, N);
    fill_kernel<<<(E + 255) / 256, 256, 0, stream>>>(edge_index, cursor, rowptr, csr, E);
    wcat_kernel<<<(2 * H * KTOT + 255) / 256, 256, 0, stream>>>(W1, root1, W2, root2, WT1, WT2);

    // layer 1: x -> h = relu(A1 @ [W1;root1] + b1)
    for (int n0 = 0; n0 < N; n0 += chunk) {
        int n1 = (n0 + chunk < N) ? n0 + chunk : N;
        int rows = n1 - n0;
        gather_kernel<<<(rows + 3) / 4, 256, 0, stream>>>(node_emb, cnt, rowptr, csr,
                                                          edge_index, edge_type, A, n0, n1, E);
        gemm_kernel<<<(rows + 127) / 128, 256, 0, stream>>>(A, WT1, b1, h, n0, n1, 1);
    }
    // layer 2: h -> out = A2 @ [W2;root2] + b2
    for (int n0 = 0; n0 < N; n0 += chunk) {
        int n1 = (n0 + chunk < N) ? n0 + chunk : N;
        int rows = n1 - n0;
        gather_kernel<<<(rows + 3) / 4, 256, 0, stream>>>(h, cnt, rowptr, csr,
                                                          edge_index, edge_type, A, n0, n1, E);
        gemm_kernel<<<(rows + 127) / 128, 256, 0, stream>>>(A, WT2, b2, out, n0, n1, 0);
    }
}

// Round 3
// 436.566 us; speedup vs baseline: 6.5713x; 1.1490x over previous
//
#include <hip/hip_runtime.h>

#define H 128
#define RREL 8
#define KTOT 1152  // RREL*H + H

typedef short bf16x8 __attribute__((ext_vector_type(8)));
typedef float f32x4 __attribute__((ext_vector_type(4)));
typedef unsigned short u16x8 __attribute__((ext_vector_type(8)));

static __device__ __forceinline__ unsigned short f2bf(float f) {
    unsigned int u = __float_as_uint(f);
    unsigned int r = (u + 0x7fffu + ((u >> 16) & 1u)) >> 16;
    return (unsigned short)r;
}
static __device__ __forceinline__ float bf2f(unsigned short u) {
    return __uint_as_float(((unsigned int)u) << 16);
}

__global__ void zero_kernel(int* p, long n) {
    long i = (long)blockIdx.x * blockDim.x + threadIdx.x;
    long stride = (long)gridDim.x * blockDim.x;
    for (; i < n; i += stride) p[i] = 0;
}

__global__ void count_kernel(const int* __restrict__ ei, const int* __restrict__ et,
                             int* __restrict__ cnt, int E) {
    int e = blockIdx.x * 256 + threadIdx.x;
    if (e >= E) return;
    int d = ei[E + e];
    int r = et[e];
    atomicAdd(&cnt[(size_t)d * RREL + r], 1);
}

// per-block exclusive scan of deg(d)=sum_r cnt[d][r]; rploc = local excl scan, bsum = block total
__global__ void scan_block_kernel(const int* __restrict__ cnt, int* __restrict__ rploc,
                                  int* __restrict__ bsum, int N) {
    __shared__ int s[256];
    int t = threadIdx.x;
    int d = blockIdx.x * 256 + t;
    int v = 0;
    if (d < N) {
#pragma unroll
        for (int r = 0; r < RREL; ++r) v += cnt[(size_t)d * RREL + r];
    }
    s[t] = v;
    __syncthreads();
#pragma unroll
    for (int off = 1; off < 256; off <<= 1) {
        int u = 0;
        if (t >= off) u = s[t - off];
        __syncthreads();
        s[t] += u;
        __syncthreads();
    }
    if (d < N) rploc[d] = s[t] - v;
    if (t == 255) bsum[blockIdx.x] = s[255];
}

__global__ void scan_top_kernel(const int* __restrict__ bsum, int* __restrict__ boff, int nb) {
    __shared__ int s[256];
    int t = threadIdx.x;
    int v = (t < nb) ? bsum[t] : 0;
    s[t] = v;
    __syncthreads();
#pragma unroll
    for (int off = 1; off < 256; off <<= 1) {
        int u = 0;
        if (t >= off) u = s[t - off];
        __syncthreads();
        s[t] += u;
        __syncthreads();
    }
    boff[t] = s[t] - v;
}

// rowptr2[d*8+r] = global bin start; inv[d*8+r] = 1/max(cnt,1); rowptr2[8N] = E
__global__ void finalize_kernel(const int* __restrict__ cnt, const int* __restrict__ rploc,
                                const int* __restrict__ boff, int* __restrict__ rowptr2,
                                float* __restrict__ inv, int N) {
    int d = blockIdx.x * 256 + threadIdx.x;
    if (d >= N) return;
    int rp = rploc[d] + boff[d >> 8];
    int run = rp;
#pragma unroll
    for (int r = 0; r < RREL; ++r) {
        int c = cnt[(size_t)d * RREL + r];
        rowptr2[(size_t)d * RREL + r] = run;
        inv[(size_t)d * RREL + r] = 1.0f / (float)max(c, 1);
        run += c;
    }
    if (d == N - 1) rowptr2[(size_t)N * RREL] = run;
}

__global__ void fill_kernel(const int* __restrict__ ei, const int* __restrict__ et,
                            int* __restrict__ cursor, const int* __restrict__ rowptr2,
                            int* __restrict__ ssrc, int E) {
    int e = blockIdx.x * 256 + threadIdx.x;
    if (e >= E) return;
    int d = ei[E + e];
    int r = et[e];
    int bin = d * RREL + r;
    int pos = rowptr2[bin] + atomicAdd(&cursor[bin], 1);
    ssrc[pos] = ei[e];
}

// x (fp32) -> bf16
__global__ void tobf_kernel(const float* __restrict__ x, unsigned short* __restrict__ xb, long n) {
    long i = (long)blockIdx.x * blockDim.x + threadIdx.x;
    long stride = (long)gridDim.x * blockDim.x;
    for (; i < n; i += stride) xb[i] = f2bf(x[i]);
}

// Build B^T (bf16): WT[f][k], k = r*128+d for k<1024 (W[r][d][f]), else root[k-1024][f]
__global__ void wcat_kernel(const float* __restrict__ W1, const float* __restrict__ r1,
                            const float* __restrict__ W2, const float* __restrict__ r2,
                            unsigned short* __restrict__ WT1, unsigned short* __restrict__ WT2) {
    int id = blockIdx.x * 256 + threadIdx.x;
    if (id >= 2 * H * KTOT) return;
    int b = id / (H * KTOT);
    int rem = id - b * (H * KTOT);
    int f = rem / KTOT;
    int k = rem - f * KTOT;
    const float* W = b ? W2 : W1;
    const float* rt = b ? r2 : r1;
    float v = (k < RREL * H) ? W[(size_t)(k >> 7) * H * H + (size_t)(k & 127) * H + f]
                             : rt[(size_t)(k - RREL * H) * H + f];
    (b ? WT2 : WT1)[(size_t)f * KTOT + k] = f2bf(v);
}

// one wave per dst; edges pre-sorted by (dst, rel); bf16 feature reads
__global__ __launch_bounds__(256) void gather_kernel(const unsigned short* __restrict__ xb,
                                                     const float* __restrict__ inv,
                                                     const int* __restrict__ rowptr2,
                                                     const int* __restrict__ ssrc,
                                                     unsigned short* __restrict__ A,
                                                     int n0, int n1) {
    const int t = threadIdx.x;
    int d = n0 + blockIdx.x * 4 + (t >> 6);
    if (d >= n1) return;
    const int l = t & 63;
    int bval = (l < 9) ? rowptr2[(size_t)d * RREL + l] : 0;
    size_t abase = (size_t)(d - n0) * KTOT + l * 2;
#pragma unroll
    for (int r = 0; r < RREL; ++r) {
        int beg = __shfl(bval, r);
        int end = __shfl(bval, r + 1);
        float ax = 0.f, ay = 0.f;
        for (int i = beg; i < end; ++i) {
            int s = ssrc[i];
            ushort2 u = *(const ushort2*)&xb[(size_t)s * H + l * 2];
            ax += bf2f(u.x);
            ay += bf2f(u.y);
        }
        float iv = inv[(size_t)d * RREL + r];
        ushort2 o;
        o.x = f2bf(ax * iv);
        o.y = f2bf(ay * iv);
        *(ushort2*)&A[abase + r * H] = o;
    }
    *(ushort2*)&A[abase + RREL * H] = *(const ushort2*)&xb[(size_t)d * H + l * 2];
}

// out[n][f] = act(sum_k A[n-n0][k]*B[k][f] + bias[f]);  B^T given as WT[f][k]
// writes fp32 to outf if non-null, else bf16 to outb
__global__ __launch_bounds__(256) void gemm_kernel(const unsigned short* __restrict__ A,
                                                   const unsigned short* __restrict__ WT,
                                                   const float* __restrict__ bias,
                                                   float* __restrict__ outf,
                                                   unsigned short* __restrict__ outb,
                                                   int n0, int n1, int relu) {
    __shared__ unsigned short As[128][72];
    __shared__ unsigned short Bs[128][72];
    const int t = threadIdx.x;
    const int w = t >> 6, l = t & 63;
    const int m_base = blockIdx.x * 128;
    const f32x4 fz = {0.f, 0.f, 0.f, 0.f};
    f32x4 acc[2][8];
#pragma unroll
    for (int mi = 0; mi < 2; ++mi)
#pragma unroll
        for (int n = 0; n < 8; ++n) acc[mi][n] = fz;

    const int rr = t >> 3;
    const int kc = (t & 7) * 8;
    const u16x8 uz = {0, 0, 0, 0, 0, 0, 0, 0};

    for (int kk = 0; kk < KTOT; kk += 64) {
#pragma unroll
        for (int p = 0; p < 4; ++p) {
            int row = p * 32 + rr;
            int gn = n0 + m_base + row;
            u16x8 va = uz;
            if (gn < n1) va = *(const u16x8*)&A[(size_t)(gn - n0) * KTOT + kk + kc];
            *(u16x8*)&As[row][kc] = va;
            u16x8 vb = *(const u16x8*)&WT[(size_t)row * KTOT + kk + kc];
            *(u16x8*)&Bs[row][kc] = vb;
        }
        __syncthreads();
#pragma unroll
        for (int ks = 0; ks < 2; ++ks) {
            int kl = ks * 32 + (l >> 4) * 8;
            bf16x8 a0 = *(const bf16x8*)&As[w * 32 + (l & 15)][kl];
            bf16x8 a1 = *(const bf16x8*)&As[w * 32 + 16 + (l & 15)][kl];
#pragma unroll
            for (int n = 0; n < 8; ++n) {
                bf16x8 b = *(const bf16x8*)&Bs[n * 16 + (l & 15)][kl];
                acc[0][n] = __builtin_amdgcn_mfma_f32_16x16x32_bf16(a0, b, acc[0][n], 0, 0, 0);
                acc[1][n] = __builtin_amdgcn_mfma_f32_16x16x32_bf16(a1, b, acc[1][n], 0, 0, 0);
            }
        }
        __syncthreads();
    }
    const int colb = l & 15, quad = l >> 4;
#pragma unroll
    for (int mi = 0; mi < 2; ++mi) {
#pragma unroll
        for (int n = 0; n < 8; ++n) {
            int col = n * 16 + colb;
            float bv = bias[col];
#pragma unroll
            for (int i = 0; i < 4; ++i) {
                int gn = n0 + m_base + w * 32 + mi * 16 + quad * 4 + i;
                if (gn < n1) {
                    float v = acc[mi][n][i] + bv;
                    if (relu) v = fmaxf(v, 0.f);
                    if (outf) outf[(size_t)gn * H + col] = v;
                    else outb[(size_t)gn * H + col] = f2bf(v);
                }
            }
        }
    }
}

extern "C" void kernel_launch(void* const* d_in, const int* in_sizes, int n_in,
                              void* d_out, int out_size, void* d_ws, size_t ws_size,
                              hipStream_t stream) {
    const int* edge_index = (const int*)d_in[0];
    const int* edge_type  = (const int*)d_in[1];
    const float* node_emb = (const float*)d_in[2];
    const float* W1    = (const float*)d_in[3];
    const float* root1 = (const float*)d_in[4];
    const float* b1    = (const float*)d_in[5];
    const float* W2    = (const float*)d_in[6];
    const float* root2 = (const float*)d_in[7];
    const float* b2    = (const float*)d_in[8];
    float* out = (float*)d_out;

    const int E = in_sizes[1];
    const int N = in_sizes[2] / H;

    // workspace layout (64B-aligned regions); cnt and cursor adjacent for single zero pass
    char* base = (char*)d_ws;
    size_t off = 0;
    auto take = [&](size_t bytes) { size_t o = off; off = (off + bytes + 63) & ~(size_t)63; return o; };
    int*   cnt     = (int*)  (base + take((size_t)N * RREL * 4));
    int*   cursor  = (int*)  (base + take((size_t)N * RREL * 4));
    int*   rploc   = (int*)  (base + take((size_t)N * 4));
    int*   bsum    = (int*)  (base + take(256 * 4));
    int*   boff    = (int*)  (base + take(256 * 4));
    int*   rowptr2 = (int*)  (base + take(((size_t)N * RREL + 1) * 4));
    float* inv     = (float*)(base + take((size_t)N * RREL * 4));
    int*   ssrc    = (int*)  (base + take((size_t)E * 4));
    unsigned short* WT1 = (unsigned short*)(base + take((size_t)H * KTOT * 2));
    unsigned short* WT2 = (unsigned short*)(base + take((size_t)H * KTOT * 2));
    unsigned short* xb  = (unsigned short*)(base + take((size_t)N * H * 2));
    unsigned short* hb  = (unsigned short*)(base + take((size_t)N * H * 2));
    size_t a_off = off;
    unsigned short* A = (unsigned short*)(base + a_off);

    size_t avail = (ws_size > a_off) ? (ws_size - a_off) : 0;
    int chunk = N;
    while ((size_t)((chunk + 127) & ~127) * KTOT * 2 > avail && chunk > 1024) chunk = (chunk + 1) / 2;
    chunk = (chunk + 127) & ~127;

    const int nbScan = (N + 255) / 256;

    zero_kernel<<<512, 256, 0, stream>>>(cnt, (long)N * RREL * 2);  // cnt + cursor
    count_kernel<<<(E + 255) / 256, 256, 0, stream>>>(edge_index, edge_type, cnt, E);
    scan_block_kernel<<<nbScan, 256, 0, stream>>>(cnt, rploc, bsum, N);
    scan_top_kernel<<<1, 256, 0, stream>>>(bsum, boff, nbScan);
    finalize_kernel<<<nbScan, 256, 0, stream>>>(cnt, rploc, boff, rowptr2, inv, N);
    fill_kernel<<<(E + 255) / 256, 256, 0, stream>>>(edge_index, edge_type, cursor, rowptr2, ssrc, E);
    wcat_kernel<<<(2 * H * KTOT + 255) / 256, 256, 0, stream>>>(W1, root1, W2, root2, WT1, WT2);
    tobf_kernel<<<1024, 256, 0, stream>>>(node_emb, xb, (long)N * H);

    // layer 1: xb -> hb = relu(A1 @ [W1;root1] + b1)  (bf16 out)
    for (int n0 = 0; n0 < N; n0 += chunk) {
        int n1 = (n0 + chunk < N) ? n0 + chunk : N;
        int rows = n1 - n0;
        gather_kernel<<<(rows + 3) / 4, 256, 0, stream>>>(xb, inv, rowptr2, ssrc, A, n0, n1);
        gemm_kernel<<<(rows + 127) / 128, 256, 0, stream>>>(A, WT1, b1, nullptr, hb, n0, n1, 1);
    }
    // layer 2: hb -> out = A2 @ [W2;root2] + b2  (fp32 out)
    for (int n0 = 0; n0 < N; n0 += chunk) {
        int n1 = (n0 + chunk < N) ? n0 + chunk : N;
        int rows = n1 - n0;
        gather_kernel<<<(rows + 3) / 4, 256, 0, stream>>>(hb, inv, rowptr2, ssrc, A, n0, n1);
        gemm_kernel<<<(rows + 127) / 128, 256, 0, stream>>>(A, WT2, b2, out, nullptr, n0, n1, 0);
    }
}